// Round 3
// baseline (488.906 us; speedup 1.0000x reference)
//
#include <hip/hip_runtime.h>
#include <hip/hip_cooperative_groups.h>
#include <stdint.h>

namespace cg = cooperative_groups;

typedef __bf16 bf16;
typedef __bf16 bf16x8 __attribute__((ext_vector_type(8)));
typedef float  f32x4  __attribute__((ext_vector_type(4)));

#define NSEQ 4096
#define NROWS 16384
#define CHUNK 32
#define NCHUNKS_B 128
#define NCHUNKS 512
#define SEGLEN 16
#define NSEG 8
#define YST 520   // padded LDS row stride (elems); 1040B = 65*16, de-banks column scans
#define YSTRIDE 516

__device__ __forceinline__ float bf2f(uint16_t u){
    uint32_t w = ((uint32_t)u) << 16;
    return __builtin_bit_cast(float, w);
}
__device__ __forceinline__ uint32_t pack2(float a, float b){
    uint16_t ua = __builtin_bit_cast(uint16_t, (bf16)a);
    uint16_t ub = __builtin_bit_cast(uint16_t, (bf16)b);
    return ((uint32_t)ub << 16) | (uint32_t)ua;
}
__device__ __forceinline__ uint4 cvt8(const float* p){
    float4 lo = *(const float4*)p;
    float4 hi = *(const float4*)(p + 4);
    uint4 r;
    r.x = pack2(lo.x, lo.y); r.y = pack2(lo.z, lo.w);
    r.z = pack2(hi.x, hi.y); r.w = pack2(hi.z, hi.w);
    return r;
}
__device__ __forceinline__ float rd_any(const void* p, long idx, int f){
    return f ? ((const float*)p)[idx] : (float)((const bf16*)p)[idx];
}
// async global->LDS, 16B per lane; ldsp must be wave-uniform (dest = ldsp + lane*16)
__device__ __forceinline__ void cp16(const void* g, void* l){
    __builtin_amdgcn_global_load_lds((const __attribute__((address_space(1))) void*)g,
                                     (__attribute__((address_space(3))) void*)l,
                                     16, 0, 0);
}

// ---- prep_all: flag detect (every block) + transpose W_i/W_o + small tensors ----
// grid = 140: blocks 0..127 transpose, 128..135 Wt_es, 136..139 decay tables
__global__ __launch_bounds__(256) void prep_all(const uint32_t* __restrict__ xw,
                                                const void* __restrict__ Wi,
                                                const void* __restrict__ Wo,
                                                const void* We, const void* Ws,
                                                const void* op, const void* g, const void* bta,
                                                bf16* __restrict__ Wt_i, bf16* __restrict__ Wt_o,
                                                bf16* __restrict__ Wt_es,
                                                float* __restrict__ g_c, float* __restrict__ b_c,
                                                float* __restrict__ o_buf, float* __restrict__ oL_buf,
                                                float* __restrict__ lsL_buf, float* __restrict__ oL16_buf,
                                                int* __restrict__ flag_g){
    __shared__ int cnt[256];
    __shared__ bf16 T[64][65];
    int tid = threadIdx.x;
    int c = 0;
    #pragma unroll
    for (int j = 0; j < 4; ++j){
        uint32_t w = xw[tid*4 + j];
        uint32_t e = (w >> 7) & 0xFF;
        c += (e >= 110 && e <= 140) ? 1 : 0;
    }
    cnt[tid] = c; __syncthreads();
    for (int s = 128; s; s >>= 1){
        if (tid < s) cnt[tid] += cnt[tid + s];
        __syncthreads();
    }
    int f = (cnt[0] < 512) ? 1 : 0;
    int blk = blockIdx.x;
    if (blk == 0 && tid == 0) flag_g[0] = f;

    if (blk < 128){
        int mat = blk >> 6;
        int t   = blk & 63;
        int k0  = (t >> 3) * 64, n0 = (t & 7) * 64;
        const void* in = mat ? Wo : Wi;
        bf16* out = mat ? Wt_o : Wt_i;
        #pragma unroll
        for (int e = 0; e < 16; ++e){
            int idx = e*256 + tid;
            int r = idx >> 6, cc = idx & 63;
            T[cc][r] = (bf16)rd_any(in, (long)(k0 + r)*512 + n0 + cc, f);
        }
        __syncthreads();
        #pragma unroll
        for (int e = 0; e < 16; ++e){
            int idx = e*256 + tid;
            int rn = idx >> 6, ck = idx & 63;
            out[(long)(n0 + rn)*512 + k0 + ck] = T[rn][ck];
        }
    } else if (blk < 136){
        int sub = blk - 128;
        for (int i = tid; i < 1024; i += 256){
            int gi = sub*1024 + i;
            int n = gi >> 9, k = gi & 511;
            float v = (n < 8) ? rd_any(We, (long)k*8 + n, f)
                              : rd_any(Ws, (long)k*8 + (n-8), f);
            Wt_es[gi] = (bf16)v;
        }
    } else {
        int sub = blk - 136;
        int base = sub * 1024;
        for (int i = tid; i < 1024; i += 256){
            int gi = base + i;
            float x = rd_any(op, gi, f);
            float ls = (x < 0.f) ? (x - log1pf(expf(x))) : (0.f - log1pf(expf(-x)));
            o_buf[gi]    = expf(ls * (1.0f/16.0f));       // o = sigmoid^(1/16)
            oL_buf[gi]   = expf(ls * 2.0f);               // o^32
            lsL_buf[gi]  = ls * 2.0f;                     // log(o^32)
            oL16_buf[gi] = expf(ls * 32.0f);              // o^512
        }
        if (sub == 0){
            for (int i = tid; i < 512; i += 256){
                g_c[i] = rd_any(g, i, f);
                b_c[i] = rd_any(bta, i, f);
            }
        }
    }
}

// ---- GEMM: C(MxN) = A(MxK) * Bt(NxK)^T, bf16 MFMA, async LDS staging ----
// Optional fused e/s projection (Wes non-null): ntile==0, wc==0 waves also
// accumulate A-tile x Wt_es (16 cols) from the already-staged LDS fragments.
__global__ __launch_bounds__(256) void gemm_bt(const void* __restrict__ Avoid,
                                               const bf16* __restrict__ Bt,
                                               void* __restrict__ Cvoid,
                                               int M, int N, int Kd,
                                               const int* __restrict__ aflag,
                                               const int* __restrict__ cflag,
                                               const bf16* __restrict__ Wes,
                                               float* __restrict__ e_out,
                                               float* __restrict__ s_out){
    __shared__ __align__(16) bf16 As[128*32];
    __shared__ __align__(16) bf16 Bs[128*32];
    const int tid  = threadIdx.x;
    const int lane = tid & 63;
    const int wave = tid >> 6;
    const int ntiles = N >> 7;
    // XCD-bijective swizzle: colocate the ntile-blocks of one mtile on one XCD
    // so the shared A panel is an L2 hit, not 4x cross-XCD refetch. 512%8==0.
    int bid = blockIdx.x;
    {
        const int q = gridDim.x >> 3;
        bid = (bid & 7) * q + (bid >> 3);
    }
    const int mtile = bid / ntiles;
    const int ntile = bid - mtile*ntiles;
    const int m0 = mtile << 7, n0 = ntile << 7;
    const int wr = (wave >> 1) << 6;
    const int wc = (wave & 1) << 6;
    const int lrow = lane & 15;
    const int quad = lane >> 4;
    const int fa = aflag ? *aflag : 0;
    const bool do_es = (Wes != nullptr) && (ntile == 0) && (wc == 0);

    f32x4 acc[4][4] = {};
    f32x4 acc_es[4] = {};

    const int sr = tid >> 2;              // staging row 0..63
    const int sk = (tid & 3) << 3;        // k offset 0/8/16/24
    const bf16*  Ag  = (const bf16*) Avoid + (long)(m0 + sr)*Kd + sk;
    const float* Agf = (const float*)Avoid + (long)(m0 + sr)*Kd + sk;
    const bf16*  Bg  = Bt + (long)(n0 + sr)*Kd + sk;

    for (int k0 = 0; k0 < Kd; k0 += 32){
        uint4 a0, a1;
        if (fa){
            a0 = cvt8(Agf + k0);
            a1 = cvt8(Agf + (long)64*Kd + k0);
        }
        if (k0) __syncthreads();          // prev iter's LDS reads done
        if (fa){
            *(uint4*)&As[tid*8]        = a0;
            *(uint4*)&As[2048 + tid*8] = a1;
        } else {
            cp16(Ag + k0,                &As[(size_t)wave*512]);
            cp16(Ag + (long)64*Kd + k0,  &As[2048 + (size_t)wave*512]);
        }
        cp16(Bg + k0,                &Bs[(size_t)wave*512]);
        cp16(Bg + (long)64*Kd + k0,  &Bs[2048 + (size_t)wave*512]);
        __syncthreads();                  // drains vmcnt+lds before use

        bf16x8 af[4], bfr[4];
        #pragma unroll
        for (int i = 0; i < 4; ++i)
            af[i]  = *(const bf16x8*)&As[(wr + i*16 + lrow)*32 + quad*8];
        #pragma unroll
        for (int j = 0; j < 4; ++j)
            bfr[j] = *(const bf16x8*)&Bs[(wc + j*16 + lrow)*32 + quad*8];
        #pragma unroll
        for (int i = 0; i < 4; ++i)
            #pragma unroll
            for (int j = 0; j < 4; ++j)
                acc[i][j] = __builtin_amdgcn_mfma_f32_16x16x32_bf16(af[i], bfr[j], acc[i][j], 0, 0, 0);
        if (do_es){
            bf16x8 be = *(const bf16x8*)(Wes + (long)lrow*512 + k0 + quad*8);
            #pragma unroll
            for (int i = 0; i < 4; ++i)
                acc_es[i] = __builtin_amdgcn_mfma_f32_16x16x32_bf16(af[i], be, acc_es[i], 0, 0, 0);
        }
    }

    const int fc = cflag ? *cflag : 0;
    // C/D layout: col = lane&15, row = quad*4 + reg
    if (fc){
        float* Cf = (float*)Cvoid;
        #pragma unroll
        for (int i = 0; i < 4; ++i){
            int gr = m0 + wr + i*16 + quad*4;
            #pragma unroll
            for (int j = 0; j < 4; ++j){
                int gc = n0 + wc + j*16 + lrow;
                #pragma unroll
                for (int r = 0; r < 4; ++r)
                    Cf[(long)(gr + r)*N + gc] = acc[i][j][r];
            }
        }
    } else {
        bf16* Cb = (bf16*)Cvoid;
        #pragma unroll
        for (int i = 0; i < 4; ++i){
            int gr = m0 + wr + i*16 + quad*4;
            #pragma unroll
            for (int j = 0; j < 4; ++j){
                int gc = n0 + wc + j*16 + lrow;
                #pragma unroll
                for (int r = 0; r < 4; ++r)
                    Cb[(long)(gr + r)*N + gc] = (bf16)acc[i][j][r];
            }
        }
    }
    if (do_es){
        // D: col=lane&15 (0..7 -> e, 8..15 -> s), row = quad*4 + reg
        float* eo = (lrow < 8) ? e_out : s_out;
        int col = lrow & 7;
        #pragma unroll
        for (int i = 0; i < 4; ++i){
            int gr = m0 + wr + i*16 + quad*4;
            #pragma unroll
            for (int r = 0; r < 4; ++r)
                eo[(long)(gr + r)*8 + col] = acc_es[i][r];
        }
    }
}

// ---- cooperative fused scan: A (local chunk states) -> B1 -> B2 -> C (+LN) ----
// Block c owns chunk c; i-chunk staged once into LDS and replayed in phase C.
__global__ __launch_bounds__(256, 2) void scan_fused(bf16* __restrict__ iy,
                                                     const float* __restrict__ e_buf,
                                                     const float* __restrict__ s_buf,
                                                     const float* __restrict__ o_buf,
                                                     const float* __restrict__ oL_buf,
                                                     const float* __restrict__ oL16_buf,
                                                     const float* __restrict__ lsL_buf,
                                                     float* __restrict__ Ams,
                                                     float* __restrict__ Tbuf,
                                                     const float* __restrict__ g_c,
                                                     const float* __restrict__ b_c){
    cg::grid_group grid = cg::this_grid();
    const int c  = blockIdx.x;           // 0..511
    const int b  = c >> 7;
    const int cI = c & 127;
    const int t0 = cI * CHUNK;
    const int tid  = threadIdx.x;
    const int lane = tid & 63;
    const int wave = tid >> 6;

    __shared__ __align__(16) bf16 iyS[CHUNK * YST];   // 32.5 KB, i then y in-place
    __shared__ float eS[CHUNK*8], sS[CHUNK*8];
    __shared__ float muS[CHUNK], rS[CHUNK];

    // stage i-chunk (32x512 bf16) into LDS: 8 rows per wave (4 waves x 8 = 32)
    bf16* gsrc = iy + ((long)(b*NSEQ + t0))*512;
    #pragma unroll
    for (int j = 0; j < 8; ++j){
        int row = wave*8 + j;
        cp16(gsrc + (long)row*512 + lane*8, &iyS[row*YST]);
    }
    eS[tid] = e_buf[((long)(b*NSEQ + t0))*8 + tid];
    sS[tid] = s_buf[((long)(b*NSEQ + t0))*8 + tid];
    __syncthreads();                      // drains cp16 vmcnt + lds

    const int d0 = tid*2;
    float o0[8], o1[8], m0v[8], m1v[8];
    #pragma unroll
    for (int k = 0; k < 8; ++k){
        o0[k] = o_buf[k*512 + d0]; o1[k] = o_buf[k*512 + d0 + 1];
        m0v[k] = 0.f; m1v[k] = 0.f;
    }
    // ---- phase A: local chunk scan from zero ----
    for (int t = 0; t < CHUNK; ++t){
        uint32_t iv = *(const uint32_t*)&iyS[t*YST + d0];
        float i0 = bf2f((uint16_t)iv), i1 = bf2f((uint16_t)(iv >> 16));
        #pragma unroll
        for (int k = 0; k < 8; ++k){
            float ek = eS[t*8 + k];
            m0v[k] = o0[k]*m0v[k] + ek*i0;
            m1v[k] = o1[k]*m1v[k] + ek*i1;
        }
    }
    {
        float* Ac = Ams + (long)c*4096;
        #pragma unroll
        for (int k = 0; k < 8; ++k){
            float2 v; v.x = m0v[k]; v.y = m1v[k];
            *(float2*)&Ac[k*512 + d0] = v;
        }
    }
    __threadfence();
    grid.sync();

    // ---- phase B1: in-place local prefix within each 16-chunk segment ----
    {
        int bs  = c >> 4;                        // b*8+seg, 0..31
        int b1  = bs >> 3, seg = bs & 7;
        int idx = (c & 15)*256 + tid;            // 0..4095
        float oL = oL_buf[idx];
        float m = 0.f;
        float* Mb = Ams + ((long)b1*NCHUNKS_B + seg*SEGLEN)*4096 + idx;
        #pragma unroll 4
        for (int cc = 0; cc < SEGLEN; ++cc){
            float a = Mb[(long)cc*4096];
            Mb[(long)cc*4096] = m;
            m = oL*m + a;
        }
        Tbuf[(long)bs*4096 + idx] = m;
    }
    __threadfence();
    grid.sync();

    // ---- phase B2: scan segment totals -> segment-start states ----
    if (c < 64){
        int b2  = c >> 4;
        int idx = (c & 15)*256 + tid;
        float oL16 = oL16_buf[idx];
        float t[NSEG];
        #pragma unroll
        for (int s = 0; s < NSEG; ++s)
            t[s] = Tbuf[((long)b2*NSEG + s)*4096 + idx];
        float m = 0.f;
        #pragma unroll
        for (int s = 0; s < NSEG; ++s){
            Tbuf[((long)b2*NSEG + s)*4096 + idx] = m;
            m = oL16*m + t[s];
        }
    }
    __threadfence();
    grid.sync();

    // ---- phase C: replay from LDS with fixup, y -> LDS (bf16), LN, store ----
    {
        int seg = cI >> 4;
        float fj = (float)(cI & 15);
        const float* P0 = Ams  + (long)c*4096;
        const float* Ms = Tbuf + ((long)b*NSEG + seg)*4096;
        #pragma unroll
        for (int k = 0; k < 8; ++k){
            int i0 = k*512 + d0;
            m0v[k] = P0[i0]   + __expf(lsL_buf[i0]  *fj)*Ms[i0];
            m1v[k] = P0[i0+1] + __expf(lsL_buf[i0+1]*fj)*Ms[i0+1];
        }
        for (int t = 0; t < CHUNK; ++t){
            uint32_t iv = *(const uint32_t*)&iyS[t*YST + d0];
            float i0 = bf2f((uint16_t)iv), i1 = bf2f((uint16_t)(iv >> 16));
            float y0 = 0.f, y1 = 0.f;
            #pragma unroll
            for (int k = 0; k < 8; ++k){
                float ek = eS[t*8 + k], sk = sS[t*8 + k];
                m0v[k] = o0[k]*m0v[k] + ek*i0;
                m1v[k] = o1[k]*m1v[k] + ek*i1;
                y0 += sk*m0v[k];
                y1 += sk*m1v[k];
            }
            *(uint32_t*)&iyS[t*YST + d0] = pack2(y0, y1);   // y over i, in place
        }
    }
    __syncthreads();
    // LN stats: wave per row, 8 rows per wave (4 waves x 8 = 32 rows)
    #pragma unroll
    for (int rr = 0; rr < 8; ++rr){
        int row = wave*8 + rr;
        uint4 u = *(const uint4*)&iyS[row*YST + lane*8];
        const uint16_t* uu = (const uint16_t*)&u;
        float s = 0.f, s2 = 0.f;
        #pragma unroll
        for (int j = 0; j < 8; ++j){
            float v = bf2f(uu[j]);
            s += v; s2 += v*v;
        }
        #pragma unroll
        for (int off = 1; off < 64; off <<= 1){
            s  += __shfl_xor(s, off);
            s2 += __shfl_xor(s2, off);
        }
        if (lane == 0){
            float mu  = s * (1.f/512.f);
            float var = s2 * (1.f/512.f) - mu*mu;
            muS[row] = mu;
            rS[row]  = rsqrtf(var + 1e-5f);
        }
    }
    __syncthreads();
    {
        float g0 = g_c[d0], g1 = g_c[d0+1];
        float bb0 = b_c[d0], bb1 = b_c[d0+1];
        bf16* ip = iy + (long)(b*NSEQ + t0)*512 + d0;
        for (int t = 0; t < CHUNK; ++t){
            float mu = muS[t], r = rS[t];
            uint32_t yv = *(const uint32_t*)&iyS[t*YST + d0];
            float a0 = (bf2f((uint16_t)yv)        - mu)*r*g0 + bb0;
            float a1 = (bf2f((uint16_t)(yv >> 16)) - mu)*r*g1 + bb1;
            *(uint32_t*)(ip + (long)t*512) = pack2(a0, a1);
        }
    }
}

// ================= fallback path (R1-proven separate kernels) =================
__global__ __launch_bounds__(256) void passA(const bf16* __restrict__ i_buf,
                                             const float* __restrict__ e_buf,
                                             const float* __restrict__ o_buf,
                                             float* __restrict__ Ams){
    int c  = blockIdx.x;
    int b  = c >> 7;
    int t0 = (c & 127) * CHUNK;
    int tid = threadIdx.x;
    __shared__ float eS[CHUNK*8];
    eS[tid] = e_buf[((long)(b*NSEQ + t0))*8 + tid];
    __syncthreads();
    int d0 = tid*2;
    float o0[8], o1[8], m0[8], m1[8];
    #pragma unroll
    for (int k = 0; k < 8; ++k){
        o0[k] = o_buf[k*512 + d0]; o1[k] = o_buf[k*512 + d0 + 1];
        m0[k] = 0.f; m1[k] = 0.f;
    }
    const bf16* ip = i_buf + (long)(b*NSEQ + t0)*512 + d0;
    for (int t = 0; t < CHUNK; ++t){
        uint32_t iv = *(const uint32_t*)(ip + (long)t*512);
        float i0 = bf2f((uint16_t)iv), i1 = bf2f((uint16_t)(iv >> 16));
        #pragma unroll
        for (int k = 0; k < 8; ++k){
            float ek = eS[t*8 + k];
            m0[k] = o0[k]*m0[k] + ek*i0;
            m1[k] = o1[k]*m1[k] + ek*i1;
        }
    }
    float* Ac = Ams + (long)c*4096;
    #pragma unroll
    for (int k = 0; k < 8; ++k){
        float2 v; v.x = m0[k]; v.y = m1[k];
        *(float2*)&Ac[k*512 + d0] = v;
    }
}

__global__ __launch_bounds__(256) void passB1(float* __restrict__ Ams,
                                              const float* __restrict__ oL_buf,
                                              float* __restrict__ Tbuf){
    int bs  = blockIdx.x >> 4;
    int b   = bs >> 3, seg = bs & 7;
    int idx = (blockIdx.x & 15)*256 + threadIdx.x;
    float oL = oL_buf[idx];
    float m = 0.f;
    float* Mb = Ams + ((long)b*NCHUNKS_B + seg*SEGLEN)*4096 + idx;
    #pragma unroll 4
    for (int cc = 0; cc < SEGLEN; ++cc){
        float a = Mb[(long)cc*4096];
        Mb[(long)cc*4096] = m;
        m = oL*m + a;
    }
    Tbuf[(long)bs*4096 + idx] = m;
}

__global__ __launch_bounds__(256) void passB2(float* __restrict__ Tbuf,
                                              const float* __restrict__ oL16_buf){
    int b   = blockIdx.x >> 4;
    int idx = (blockIdx.x & 15)*256 + threadIdx.x;
    float oL16 = oL16_buf[idx];
    float t[NSEG];
    #pragma unroll
    for (int s = 0; s < NSEG; ++s)
        t[s] = Tbuf[((long)b*NSEG + s)*4096 + idx];
    float m = 0.f;
    #pragma unroll
    for (int s = 0; s < NSEG; ++s){
        Tbuf[((long)b*NSEG + s)*4096 + idx] = m;
        m = oL16*m + t[s];
    }
}

__global__ __launch_bounds__(256) void passC(bf16* __restrict__ iy,
                                             const float* __restrict__ e_buf,
                                             const float* __restrict__ s_buf,
                                             const float* __restrict__ o_buf,
                                             const float* __restrict__ Ploc,
                                             const float* __restrict__ Mseg,
                                             const float* __restrict__ lsL_buf,
                                             const float* __restrict__ g_c,
                                             const float* __restrict__ b_c){
    int c  = blockIdx.x;
    int b  = c >> 7;
    int cI = c & 127;
    int seg = cI >> 4;
    float fj = (float)(cI & 15);
    int t0 = cI * CHUNK;
    int tid = threadIdx.x;
    __shared__ float eS[CHUNK*8], sS[CHUNK*8];
    __shared__ float muS[CHUNK], rS[CHUNK];
    __shared__ __align__(16) float yS[CHUNK][YSTRIDE];
    eS[tid] = e_buf[((long)(b*NSEQ + t0))*8 + tid];
    sS[tid] = s_buf[((long)(b*NSEQ + t0))*8 + tid];
    __syncthreads();
    int d0 = tid*2;
    float o0[8], o1[8], m0[8], m1[8];
    const float* P0 = Ploc + (long)c*4096;
    const float* Ms = Mseg + ((long)b*NSEG + seg)*4096;
    #pragma unroll
    for (int k = 0; k < 8; ++k){
        int i0 = k*512 + d0;
        o0[k] = o_buf[i0]; o1[k] = o_buf[i0 + 1];
        m0[k] = P0[i0]   + __expf(lsL_buf[i0]  *fj)*Ms[i0];
        m1[k] = P0[i0+1] + __expf(lsL_buf[i0+1]*fj)*Ms[i0+1];
    }
    bf16* ip = iy + (long)(b*NSEQ + t0)*512 + d0;
    for (int t = 0; t < CHUNK; ++t){
        uint32_t iv = *(const uint32_t*)(ip + (long)t*512);
        float i0 = bf2f((uint16_t)iv), i1 = bf2f((uint16_t)(iv >> 16));
        float y0 = 0.f, y1 = 0.f;
        #pragma unroll
        for (int k = 0; k < 8; ++k){
            float ek = eS[t*8 + k], sk = sS[t*8 + k];
            m0[k] = o0[k]*m0[k] + ek*i0;
            m1[k] = o1[k]*m1[k] + ek*i1;
            y0 += sk*m0[k];
            y1 += sk*m1[k];
        }
        float2 yv; yv.x = y0; yv.y = y1;
        *(float2*)&yS[t][d0] = yv;
    }
    __syncthreads();
    {
        int row = tid >> 3, sub = tid & 7;
        const float4* yr = (const float4*)&yS[row][sub*64];
        float s = 0.f, s2 = 0.f;
        #pragma unroll
        for (int j = 0; j < 16; ++j){
            float4 v = yr[j];
            s  += v.x + v.y + v.z + v.w;
            s2 += v.x*v.x + v.y*v.y + v.z*v.z + v.w*v.w;
        }
        s += __shfl_xor(s, 1); s2 += __shfl_xor(s2, 1);
        s += __shfl_xor(s, 2); s2 += __shfl_xor(s2, 2);
        s += __shfl_xor(s, 4); s2 += __shfl_xor(s2, 4);
        if (sub == 0){
            float mu  = s * (1.f/512.f);
            float var = s2 * (1.f/512.f) - mu*mu;
            muS[row] = mu;
            rS[row]  = rsqrtf(var + 1e-5f);
        }
    }
    __syncthreads();
    float g0 = g_c[d0], g1 = g_c[d0+1];
    float bb0 = b_c[d0], bb1 = b_c[d0+1];
    for (int t = 0; t < CHUNK; ++t){
        float mu = muS[t], r = rS[t];
        float2 yv = *(const float2*)&yS[t][d0];
        float a0 = (yv.x - mu)*r*g0 + bb0;
        float a1 = (yv.y - mu)*r*g1 + bb1;
        *(uint32_t*)(ip + (long)t*512) = pack2(a0, a1);
    }
}

extern "C" void kernel_launch(void* const* d_in, const int* in_sizes, int n_in,
                              void* d_out, int out_size, void* d_ws, size_t ws_size,
                              hipStream_t stream){
    const void* x    = d_in[0];
    const void* W_i  = d_in[1];
    const void* W_e  = d_in[2];
    const void* W_s  = d_in[3];
    const void* o_p  = d_in[4];
    const void* gmm  = d_in[5];
    const void* bta  = d_in[6];
    const void* W_o  = d_in[7];

    char* ws = (char*)d_ws;
    bf16*  Wt_i   = (bf16*) (ws + 0);          // 512 KB (dead after gemm1)
    float* Tbuf   = (float*)(ws + 0);          // aliased: B1 totals / B2 seg-starts
    bf16*  Wt_o   = (bf16*) (ws + 524288);     // 512 KB
    bf16*  iy_buf = (bf16*) (ws + 1048576);    // 16 MB (i, then y in-place)
    float* e_buf  = (float*)(ws + 17825792);   // 512 KB
    float* s_buf  = (float*)(ws + 18350080);   // 512 KB
    float* o_buf  = (float*)(ws + 18874368);   // 16 KB
    float* oL_buf = (float*)(ws + 18890752);   // 16 KB
    float* lsL    = (float*)(ws + 18907136);   // 16 KB
    float* oL16   = (float*)(ws + 18923520);   // 16 KB
    float* Ams    = (float*)(ws + 18939904);   // 8 MB (A, then local prefixes)
    bf16*  Wt_es  = (bf16*) (ws + 27328512);   // 16 KB
    float* g_c    = (float*)(ws + 27344896);   // 2 KB
    float* b_c    = (float*)(ws + 27346944);   // 2 KB
    int*   flag   = (int*)  (ws + 27348992);   // 256 B  (total ~26.1 MB)

    prep_all<<<140, 256, 0, stream>>>((const uint32_t*)x, W_i, W_o, W_e, W_s, o_p, gmm, bta,
                                      Wt_i, Wt_o, Wt_es, g_c, b_c, o_buf, oL_buf, lsL, oL16, flag);
    gemm_bt <<<512, 256, 0, stream>>>(x, Wt_i, iy_buf, NROWS, 512, 512, flag, nullptr,
                                      Wt_es, e_buf, s_buf);
    {
        void* args[] = { (void*)&iy_buf, (void*)&e_buf, (void*)&s_buf, (void*)&o_buf,
                         (void*)&oL_buf, (void*)&oL16, (void*)&lsL, (void*)&Ams,
                         (void*)&Tbuf, (void*)&g_c, (void*)&b_c };
        hipError_t cerr = hipLaunchCooperativeKernel((const void*)scan_fused, dim3(NCHUNKS),
                                                     dim3(256), args, 0, stream);
        if (cerr != hipSuccess){
            // fallback: proven 4-kernel path
            passA <<<NCHUNKS, 256, 0, stream>>>(iy_buf, e_buf, o_buf, Ams);
            passB1<<<512,    256, 0, stream>>>(Ams, oL_buf, Tbuf);
            passB2<<<64,     256, 0, stream>>>(Tbuf, oL16);
            passC <<<NCHUNKS, 256, 0, stream>>>(iy_buf, e_buf, s_buf, o_buf, Ams, Tbuf, lsL,
                                                g_c, b_c);
        }
    }
    gemm_bt <<<512, 256, 0, stream>>>(iy_buf, Wt_o, d_out, NROWS, 512, 512, nullptr, flag,
                                      nullptr, nullptr, nullptr);
}

// Round 4
// 174.818 us; speedup vs baseline: 2.7967x; 2.7967x over previous
//
#include <hip/hip_runtime.h>
#include <stdint.h>

typedef __bf16 bf16;
typedef __bf16 bf16x8 __attribute__((ext_vector_type(8)));
typedef float  f32x4  __attribute__((ext_vector_type(4)));

#define NSEQ 4096
#define NROWS 16384
#define CHUNK 32
#define NCHUNKS_B 128
#define NCHUNKS 512
#define SEGLEN 16
#define NSEG 8
#define YSTRIDE 516

__device__ __forceinline__ float bf2f(uint16_t u){
    uint32_t w = ((uint32_t)u) << 16;
    return __builtin_bit_cast(float, w);
}
__device__ __forceinline__ uint32_t pack2(float a, float b){
    uint16_t ua = __builtin_bit_cast(uint16_t, (bf16)a);
    uint16_t ub = __builtin_bit_cast(uint16_t, (bf16)b);
    return ((uint32_t)ub << 16) | (uint32_t)ua;
}
__device__ __forceinline__ uint4 cvt8(const float* p){
    float4 lo = *(const float4*)p;
    float4 hi = *(const float4*)(p + 4);
    uint4 r;
    r.x = pack2(lo.x, lo.y); r.y = pack2(lo.z, lo.w);
    r.z = pack2(hi.x, hi.y); r.w = pack2(hi.z, hi.w);
    return r;
}
__device__ __forceinline__ float rd_any(const void* p, long idx, int f){
    return f ? ((const float*)p)[idx] : (float)((const bf16*)p)[idx];
}
// async global->LDS, 16B per lane; ldsp must be wave-uniform (dest = ldsp + lane*16)
__device__ __forceinline__ void cp16(const void* g, void* l){
    __builtin_amdgcn_global_load_lds((const __attribute__((address_space(1))) void*)g,
                                     (__attribute__((address_space(3))) void*)l,
                                     16, 0, 0);
}

// ---- prep_all: flag detect (every block) + transpose W_i/W_o + small tensors ----
// grid = 140: blocks 0..127 transpose, 128..135 Wt_es, 136..139 decay tables
__global__ __launch_bounds__(256) void prep_all(const uint32_t* __restrict__ xw,
                                                const void* __restrict__ Wi,
                                                const void* __restrict__ Wo,
                                                const void* We, const void* Ws,
                                                const void* op, const void* g, const void* bta,
                                                bf16* __restrict__ Wt_i, bf16* __restrict__ Wt_o,
                                                bf16* __restrict__ Wt_es,
                                                float* __restrict__ g_c, float* __restrict__ b_c,
                                                float* __restrict__ o_buf, float* __restrict__ oL_buf,
                                                float* __restrict__ lsL_buf, float* __restrict__ oL16_buf,
                                                int* __restrict__ flag_g){
    __shared__ int cnt[256];
    __shared__ bf16 T[64][65];
    int tid = threadIdx.x;
    int c = 0;
    #pragma unroll
    for (int j = 0; j < 4; ++j){
        uint32_t w = xw[tid*4 + j];
        uint32_t e = (w >> 7) & 0xFF;
        c += (e >= 110 && e <= 140) ? 1 : 0;
    }
    cnt[tid] = c; __syncthreads();
    for (int s = 128; s; s >>= 1){
        if (tid < s) cnt[tid] += cnt[tid + s];
        __syncthreads();
    }
    int f = (cnt[0] < 512) ? 1 : 0;
    int blk = blockIdx.x;
    if (blk == 0 && tid == 0) flag_g[0] = f;

    if (blk < 128){
        int mat = blk >> 6;
        int t   = blk & 63;
        int k0  = (t >> 3) * 64, n0 = (t & 7) * 64;
        const void* in = mat ? Wo : Wi;
        bf16* out = mat ? Wt_o : Wt_i;
        #pragma unroll
        for (int e = 0; e < 16; ++e){
            int idx = e*256 + tid;
            int r = idx >> 6, cc = idx & 63;
            T[cc][r] = (bf16)rd_any(in, (long)(k0 + r)*512 + n0 + cc, f);
        }
        __syncthreads();
        #pragma unroll
        for (int e = 0; e < 16; ++e){
            int idx = e*256 + tid;
            int rn = idx >> 6, ck = idx & 63;
            out[(long)(n0 + rn)*512 + k0 + ck] = T[rn][ck];
        }
    } else if (blk < 136){
        int sub = blk - 128;
        for (int i = tid; i < 1024; i += 256){
            int gi = sub*1024 + i;
            int n = gi >> 9, k = gi & 511;
            float v = (n < 8) ? rd_any(We, (long)k*8 + n, f)
                              : rd_any(Ws, (long)k*8 + (n-8), f);
            Wt_es[gi] = (bf16)v;
        }
    } else {
        int sub = blk - 136;
        int base = sub * 1024;
        for (int i = tid; i < 1024; i += 256){
            int gi = base + i;
            float x = rd_any(op, gi, f);
            float ls = (x < 0.f) ? (x - log1pf(expf(x))) : (0.f - log1pf(expf(-x)));
            o_buf[gi]    = expf(ls * (1.0f/16.0f));       // o = sigmoid^(1/16)
            oL_buf[gi]   = expf(ls * 2.0f);               // o^32
            lsL_buf[gi]  = ls * 2.0f;                     // log(o^32)
            oL16_buf[gi] = expf(ls * 32.0f);              // o^512
        }
        if (sub == 0){
            for (int i = tid; i < 512; i += 256){
                g_c[i] = rd_any(g, i, f);
                b_c[i] = rd_any(bta, i, f);
            }
        }
    }
}

// ---- GEMM: C(MxN) = A(MxK) * Bt(NxK)^T, bf16 MFMA ----
// 2-phase double-buffered LDS pipeline: stage tile t+1 BEFORE computing tile t,
// single barrier per k-iter; staging latency hides under ds_read+MFMA (T3-min).
// Optional fused e/s projection (Wes non-null): ntile==0, wc==0 waves also
// accumulate A-tile x Wt_es (16 cols) from the already-staged LDS fragments.
__global__ __launch_bounds__(256) void gemm_bt(const void* __restrict__ Avoid,
                                               const bf16* __restrict__ Bt,
                                               void* __restrict__ Cvoid,
                                               int M, int N, int Kd,
                                               const int* __restrict__ aflag,
                                               const int* __restrict__ cflag,
                                               const bf16* __restrict__ Wes,
                                               float* __restrict__ e_out,
                                               float* __restrict__ s_out){
    __shared__ __align__(16) bf16 As[2][128*32];
    __shared__ __align__(16) bf16 Bs[2][128*32];
    const int tid  = threadIdx.x;
    const int lane = tid & 63;
    const int wave = tid >> 6;
    const int ntiles = N >> 7;
    // XCD-bijective swizzle: colocate the ntile-blocks of one mtile on one XCD
    // so the shared A panel is an L2 hit, not 4x cross-XCD refetch. 512%8==0.
    int bid = blockIdx.x;
    {
        const int q = gridDim.x >> 3;
        bid = (bid & 7) * q + (bid >> 3);
    }
    const int mtile = bid / ntiles;
    const int ntile = bid - mtile*ntiles;
    const int m0 = mtile << 7, n0 = ntile << 7;
    const int wr = (wave >> 1) << 6;
    const int wc = (wave & 1) << 6;
    const int lrow = lane & 15;
    const int quad = lane >> 4;
    const int fa = aflag ? *aflag : 0;
    const bool do_es = (Wes != nullptr) && (ntile == 0) && (wc == 0);

    f32x4 acc[4][4] = {};
    f32x4 acc_es[4] = {};

    const int sr = tid >> 2;              // staging row 0..63
    const int sk = (tid & 3) << 3;        // k offset 0/8/16/24
    const bf16*  Ag  = (const bf16*) Avoid + (long)(m0 + sr)*Kd + sk;
    const float* Agf = (const float*)Avoid + (long)(m0 + sr)*Kd + sk;
    const bf16*  Bg  = Bt + (long)(n0 + sr)*Kd + sk;

    // prologue: stage tile 0 into buffer 0
    if (fa){
        *(uint4*)&As[0][tid*8]        = cvt8(Agf);
        *(uint4*)&As[0][2048 + tid*8] = cvt8(Agf + (long)64*Kd);
    } else {
        cp16(Ag,                 &As[0][(size_t)wave*512]);
        cp16(Ag + (long)64*Kd,   &As[0][2048 + (size_t)wave*512]);
    }
    cp16(Bg,               &Bs[0][(size_t)wave*512]);
    cp16(Bg + (long)64*Kd, &Bs[0][2048 + (size_t)wave*512]);
    __syncthreads();                      // implicit vmcnt(0)+lgkmcnt(0) drain

    int cur = 0;
    for (int k0 = 0; k0 < Kd; k0 += 32){
        const int nxt  = cur ^ 1;
        const int k1   = k0 + 32;
        const bool more = (k1 < Kd);
        float4 la0, la1, lb0, lb1;
        if (more){
            if (fa){
                // issue raw fp32 loads now; convert+ds_write after the MFMAs
                la0 = *(const float4*)(Agf + k1);
                la1 = *(const float4*)(Agf + k1 + 4);
                lb0 = *(const float4*)(Agf + (long)64*Kd + k1);
                lb1 = *(const float4*)(Agf + (long)64*Kd + k1 + 4);
            } else {
                cp16(Ag + k1,               &As[nxt][(size_t)wave*512]);
                cp16(Ag + (long)64*Kd + k1, &As[nxt][2048 + (size_t)wave*512]);
            }
            cp16(Bg + k1,               &Bs[nxt][(size_t)wave*512]);
            cp16(Bg + (long)64*Kd + k1, &Bs[nxt][2048 + (size_t)wave*512]);
        }

        bf16x8 af[4], bfr[4];
        #pragma unroll
        for (int i = 0; i < 4; ++i)
            af[i]  = *(const bf16x8*)&As[cur][(wr + i*16 + lrow)*32 + quad*8];
        #pragma unroll
        for (int j = 0; j < 4; ++j)
            bfr[j] = *(const bf16x8*)&Bs[cur][(wc + j*16 + lrow)*32 + quad*8];
        #pragma unroll
        for (int i = 0; i < 4; ++i)
            #pragma unroll
            for (int j = 0; j < 4; ++j)
                acc[i][j] = __builtin_amdgcn_mfma_f32_16x16x32_bf16(af[i], bfr[j], acc[i][j], 0, 0, 0);
        if (do_es){
            bf16x8 be = *(const bf16x8*)(Wes + (long)lrow*512 + k0 + quad*8);
            #pragma unroll
            for (int i = 0; i < 4; ++i)
                acc_es[i] = __builtin_amdgcn_mfma_f32_16x16x32_bf16(af[i], be, acc_es[i], 0, 0, 0);
        }

        if (more && fa){
            uint4 A0, A1;
            A0.x = pack2(la0.x, la0.y); A0.y = pack2(la0.z, la0.w);
            A0.z = pack2(la1.x, la1.y); A0.w = pack2(la1.z, la1.w);
            A1.x = pack2(lb0.x, lb0.y); A1.y = pack2(lb0.z, lb0.w);
            A1.z = pack2(lb1.x, lb1.y); A1.w = pack2(lb1.z, lb1.w);
            *(uint4*)&As[nxt][tid*8]        = A0;
            *(uint4*)&As[nxt][2048 + tid*8] = A1;
        }
        __syncthreads();                  // tile t reads done + tile t+1 staged
        cur = nxt;
    }

    const int fc = cflag ? *cflag : 0;
    // C/D layout: col = lane&15, row = quad*4 + reg
    if (fc){
        float* Cf = (float*)Cvoid;
        #pragma unroll
        for (int i = 0; i < 4; ++i){
            int gr = m0 + wr + i*16 + quad*4;
            #pragma unroll
            for (int j = 0; j < 4; ++j){
                int gc = n0 + wc + j*16 + lrow;
                #pragma unroll
                for (int r = 0; r < 4; ++r)
                    Cf[(long)(gr + r)*N + gc] = acc[i][j][r];
            }
        }
    } else {
        bf16* Cb = (bf16*)Cvoid;
        #pragma unroll
        for (int i = 0; i < 4; ++i){
            int gr = m0 + wr + i*16 + quad*4;
            #pragma unroll
            for (int j = 0; j < 4; ++j){
                int gc = n0 + wc + j*16 + lrow;
                #pragma unroll
                for (int r = 0; r < 4; ++r)
                    Cb[(long)(gr + r)*N + gc] = (bf16)acc[i][j][r];
            }
        }
    }
    if (do_es){
        // D: col=lane&15 (0..7 -> e, 8..15 -> s), row = quad*4 + reg
        float* eo = (lrow < 8) ? e_out : s_out;
        int col = lrow & 7;
        #pragma unroll
        for (int i = 0; i < 4; ++i){
            int gr = m0 + wr + i*16 + quad*4;
            #pragma unroll
            for (int r = 0; r < 4; ++r)
                eo[(long)(gr + r)*8 + col] = acc_es[i][r];
        }
    }
}

// ---- pass A: per-chunk local state (from zero), 32 steps ----
__global__ __launch_bounds__(256) void passA(const bf16* __restrict__ i_buf,
                                             const float* __restrict__ e_buf,
                                             const float* __restrict__ o_buf,
                                             float* __restrict__ Ams){
    int c  = blockIdx.x;
    int b  = c >> 7;
    int t0 = (c & 127) * CHUNK;
    int tid = threadIdx.x;
    __shared__ float eS[CHUNK*8];
    eS[tid] = e_buf[((long)(b*NSEQ + t0))*8 + tid];
    __syncthreads();
    int d0 = tid*2;
    float o0[8], o1[8], m0[8], m1[8];
    #pragma unroll
    for (int k = 0; k < 8; ++k){
        o0[k] = o_buf[k*512 + d0]; o1[k] = o_buf[k*512 + d0 + 1];
        m0[k] = 0.f; m1[k] = 0.f;
    }
    const bf16* ip = i_buf + (long)(b*NSEQ + t0)*512 + d0;
    for (int t = 0; t < CHUNK; ++t){
        uint32_t iv = *(const uint32_t*)(ip + (long)t*512);
        float i0 = bf2f((uint16_t)iv), i1 = bf2f((uint16_t)(iv >> 16));
        #pragma unroll
        for (int k = 0; k < 8; ++k){
            float ek = eS[t*8 + k];
            m0[k] = o0[k]*m0[k] + ek*i0;
            m1[k] = o1[k]*m1[k] + ek*i1;
        }
    }
    float* Ac = Ams + (long)c*4096;
    #pragma unroll
    for (int k = 0; k < 8; ++k){
        float2 v; v.x = m0[k]; v.y = m1[k];
        *(float2*)&Ac[k*512 + d0] = v;
    }
}

// ---- B1: in-place local prefix within each 16-chunk segment + totals ----
__global__ __launch_bounds__(256) void passB1(float* __restrict__ Ams,
                                              const float* __restrict__ oL_buf,
                                              float* __restrict__ Tbuf){
    int bs  = blockIdx.x >> 4;                       // b*8+seg, 0..31
    int b   = bs >> 3, seg = bs & 7;
    int idx = (blockIdx.x & 15)*256 + threadIdx.x;   // 0..4095
    float oL = oL_buf[idx];
    float m = 0.f;
    float* Mb = Ams + ((long)b*NCHUNKS_B + seg*SEGLEN)*4096 + idx;
    #pragma unroll 4
    for (int cc = 0; cc < SEGLEN; ++cc){
        float a = Mb[(long)cc*4096];
        Mb[(long)cc*4096] = m;
        m = oL*m + a;
    }
    Tbuf[(long)bs*4096 + idx] = m;
}

// ---- B2: scan segment totals in registers -> segment-start states ----
__global__ __launch_bounds__(256) void passB2(float* __restrict__ Tbuf,
                                              const float* __restrict__ oL16_buf){
    int b   = blockIdx.x >> 4;
    int idx = (blockIdx.x & 15)*256 + threadIdx.x;
    float oL16 = oL16_buf[idx];
    float t[NSEG];
    #pragma unroll
    for (int s = 0; s < NSEG; ++s)
        t[s] = Tbuf[((long)b*NSEG + s)*4096 + idx];
    float m = 0.f;
    #pragma unroll
    for (int s = 0; s < NSEG; ++s){
        Tbuf[((long)b*NSEG + s)*4096 + idx] = m;
        m = oL16*m + t[s];
    }
}

// ---- pass C: replay chunk (with segment fixup) + fused LayerNorm ----
__global__ __launch_bounds__(256) void passC(bf16* __restrict__ iy,
                                             const float* __restrict__ e_buf,
                                             const float* __restrict__ s_buf,
                                             const float* __restrict__ o_buf,
                                             const float* __restrict__ Ploc,
                                             const float* __restrict__ Mseg,
                                             const float* __restrict__ lsL_buf,
                                             const float* __restrict__ g_c,
                                             const float* __restrict__ b_c){
    int c  = blockIdx.x;
    int b  = c >> 7;
    int cI = c & 127;
    int seg = cI >> 4;
    float fj = (float)(cI & 15);
    int t0 = cI * CHUNK;
    int tid = threadIdx.x;
    __shared__ float eS[CHUNK*8], sS[CHUNK*8];
    __shared__ float muS[CHUNK], rS[CHUNK];
    __shared__ __align__(16) float yS[CHUNK][YSTRIDE];
    eS[tid] = e_buf[((long)(b*NSEQ + t0))*8 + tid];
    sS[tid] = s_buf[((long)(b*NSEQ + t0))*8 + tid];
    __syncthreads();
    int d0 = tid*2;
    float o0[8], o1[8], m0[8], m1[8];
    const float* P0 = Ploc + (long)c*4096;
    const float* Ms = Mseg + ((long)b*NSEG + seg)*4096;
    #pragma unroll
    for (int k = 0; k < 8; ++k){
        int i0 = k*512 + d0;
        o0[k] = o_buf[i0]; o1[k] = o_buf[i0 + 1];
        m0[k] = P0[i0]   + __expf(lsL_buf[i0]  *fj)*Ms[i0];
        m1[k] = P0[i0+1] + __expf(lsL_buf[i0+1]*fj)*Ms[i0+1];
    }
    bf16* ip = iy + (long)(b*NSEQ + t0)*512 + d0;
    for (int t = 0; t < CHUNK; ++t){
        uint32_t iv = *(const uint32_t*)(ip + (long)t*512);
        float i0 = bf2f((uint16_t)iv), i1 = bf2f((uint16_t)(iv >> 16));
        float y0 = 0.f, y1 = 0.f;
        #pragma unroll
        for (int k = 0; k < 8; ++k){
            float ek = eS[t*8 + k], sk = sS[t*8 + k];
            m0[k] = o0[k]*m0[k] + ek*i0;
            m1[k] = o1[k]*m1[k] + ek*i1;
            y0 += sk*m0[k];
            y1 += sk*m1[k];
        }
        float2 yv; yv.x = y0; yv.y = y1;
        *(float2*)&yS[t][d0] = yv;
    }
    __syncthreads();
    {
        int row = tid >> 3, sub = tid & 7;
        const float4* yr = (const float4*)&yS[row][sub*64];
        float s = 0.f, s2 = 0.f;
        #pragma unroll
        for (int j = 0; j < 16; ++j){
            float4 v = yr[j];
            s  += v.x + v.y + v.z + v.w;
            s2 += v.x*v.x + v.y*v.y + v.z*v.z + v.w*v.w;
        }
        s += __shfl_xor(s, 1); s2 += __shfl_xor(s2, 1);
        s += __shfl_xor(s, 2); s2 += __shfl_xor(s2, 2);
        s += __shfl_xor(s, 4); s2 += __shfl_xor(s2, 4);
        if (sub == 0){
            float mu  = s * (1.f/512.f);
            float var = s2 * (1.f/512.f) - mu*mu;
            muS[row] = mu;
            rS[row]  = rsqrtf(var + 1e-5f);
        }
    }
    __syncthreads();
    float g0 = g_c[d0], g1 = g_c[d0+1];
    float bb0 = b_c[d0], bb1 = b_c[d0+1];
    for (int t = 0; t < CHUNK; ++t){
        float mu = muS[t], r = rS[t];
        float2 yv = *(const float2*)&yS[t][d0];
        float a0 = (yv.x - mu)*r*g0 + bb0;
        float a1 = (yv.y - mu)*r*g1 + bb1;
        *(uint32_t*)(ip + (long)t*512) = pack2(a0, a1);
    }
}

extern "C" void kernel_launch(void* const* d_in, const int* in_sizes, int n_in,
                              void* d_out, int out_size, void* d_ws, size_t ws_size,
                              hipStream_t stream){
    const void* x    = d_in[0];
    const void* W_i  = d_in[1];
    const void* W_e  = d_in[2];
    const void* W_s  = d_in[3];
    const void* o_p  = d_in[4];
    const void* gmm  = d_in[5];
    const void* bta  = d_in[6];
    const void* W_o  = d_in[7];

    char* ws = (char*)d_ws;
    bf16*  Wt_i   = (bf16*) (ws + 0);          // 512 KB (dead after gemm1)
    float* Tbuf   = (float*)(ws + 0);          // aliased: B1 totals / B2 seg-starts
    bf16*  Wt_o   = (bf16*) (ws + 524288);     // 512 KB
    bf16*  iy_buf = (bf16*) (ws + 1048576);    // 16 MB (i, then y in-place)
    float* e_buf  = (float*)(ws + 17825792);   // 512 KB
    float* s_buf  = (float*)(ws + 18350080);   // 512 KB
    float* o_buf  = (float*)(ws + 18874368);   // 16 KB
    float* oL_buf = (float*)(ws + 18890752);   // 16 KB
    float* lsL    = (float*)(ws + 18907136);   // 16 KB
    float* oL16   = (float*)(ws + 18923520);   // 16 KB
    float* Ams    = (float*)(ws + 18939904);   // 8 MB (A, then local prefixes)
    bf16*  Wt_es  = (bf16*) (ws + 27328512);   // 16 KB
    float* g_c    = (float*)(ws + 27344896);   // 2 KB
    float* b_c    = (float*)(ws + 27346944);   // 2 KB
    int*   flag   = (int*)  (ws + 27348992);   // 256 B  (total ~26.1 MB)

    prep_all<<<140, 256, 0, stream>>>((const uint32_t*)x, W_i, W_o, W_e, W_s, o_p, gmm, bta,
                                      Wt_i, Wt_o, Wt_es, g_c, b_c, o_buf, oL_buf, lsL, oL16, flag);
    gemm_bt <<<512, 256, 0, stream>>>(x, Wt_i, iy_buf, NROWS, 512, 512, flag, nullptr,
                                      Wt_es, e_buf, s_buf);
    passA  <<<NCHUNKS, 256, 0, stream>>>(iy_buf, e_buf, o_buf, Ams);
    passB1 <<<512,  256, 0, stream>>>(Ams, oL_buf, Tbuf);
    passB2 <<<64,   256, 0, stream>>>(Tbuf, oL16);
    passC  <<<NCHUNKS, 256, 0, stream>>>(iy_buf, e_buf, s_buf, o_buf, Ams, Tbuf, lsL,
                                         g_c, b_c);
    gemm_bt <<<512, 256, 0, stream>>>(iy_buf, Wt_o, d_out, NROWS, 512, 512, nullptr, flag,
                                      nullptr, nullptr, nullptr);
}

// Round 5
// 173.431 us; speedup vs baseline: 2.8190x; 1.0080x over previous
//
#include <hip/hip_runtime.h>
#include <stdint.h>

typedef __bf16 bf16;
typedef __bf16 bf16x8 __attribute__((ext_vector_type(8)));
typedef float  f32x4  __attribute__((ext_vector_type(4)));

#define NSEQ 4096
#define NROWS 16384
#define CHUNK 32
#define NCHUNKS_B 128
#define NCHUNKS 512
#define SEGLEN 16
#define NSEG 8
#define YSTRIDE 516

__device__ __forceinline__ float bf2f(uint16_t u){
    uint32_t w = ((uint32_t)u) << 16;
    return __builtin_bit_cast(float, w);
}
__device__ __forceinline__ uint32_t pack2(float a, float b){
    uint16_t ua = __builtin_bit_cast(uint16_t, (bf16)a);
    uint16_t ub = __builtin_bit_cast(uint16_t, (bf16)b);
    return ((uint32_t)ub << 16) | (uint32_t)ua;
}
__device__ __forceinline__ uint4 cvt8(const float* p){
    float4 lo = *(const float4*)p;
    float4 hi = *(const float4*)(p + 4);
    uint4 r;
    r.x = pack2(lo.x, lo.y); r.y = pack2(lo.z, lo.w);
    r.z = pack2(hi.x, hi.y); r.w = pack2(hi.z, hi.w);
    return r;
}
__device__ __forceinline__ float rd_any(const void* p, long idx, int f){
    return f ? ((const float*)p)[idx] : (float)((const bf16*)p)[idx];
}
// async global->LDS, 16B per lane; ldsp must be wave-uniform (dest = ldsp + lane*16)
__device__ __forceinline__ void cp16(const void* g, void* l){
    __builtin_amdgcn_global_load_lds((const __attribute__((address_space(1))) void*)g,
                                     (__attribute__((address_space(3))) void*)l,
                                     16, 0, 0);
}

// ---- prep_all: flag detect (every block) + transpose W_i/W_o + small tensors ----
// grid = 140: blocks 0..127 transpose, 128..135 Wt_es, 136..139 decay tables
__global__ __launch_bounds__(256) void prep_all(const uint32_t* __restrict__ xw,
                                                const void* __restrict__ Wi,
                                                const void* __restrict__ Wo,
                                                const void* We, const void* Ws,
                                                const void* op, const void* g, const void* bta,
                                                bf16* __restrict__ Wt_i, bf16* __restrict__ Wt_o,
                                                bf16* __restrict__ Wt_es,
                                                float* __restrict__ g_c, float* __restrict__ b_c,
                                                float* __restrict__ o_buf, float* __restrict__ oL_buf,
                                                float* __restrict__ lsL_buf, float* __restrict__ oL16_buf,
                                                int* __restrict__ flag_g){
    __shared__ int cnt[256];
    __shared__ bf16 T[64][65];
    int tid = threadIdx.x;
    int c = 0;
    #pragma unroll
    for (int j = 0; j < 4; ++j){
        uint32_t w = xw[tid*4 + j];
        uint32_t e = (w >> 7) & 0xFF;
        c += (e >= 110 && e <= 140) ? 1 : 0;
    }
    cnt[tid] = c; __syncthreads();
    for (int s = 128; s; s >>= 1){
        if (tid < s) cnt[tid] += cnt[tid + s];
        __syncthreads();
    }
    int f = (cnt[0] < 512) ? 1 : 0;
    int blk = blockIdx.x;
    if (blk == 0 && tid == 0) flag_g[0] = f;

    if (blk < 128){
        int mat = blk >> 6;
        int t   = blk & 63;
        int k0  = (t >> 3) * 64, n0 = (t & 7) * 64;
        const void* in = mat ? Wo : Wi;
        bf16* out = mat ? Wt_o : Wt_i;
        #pragma unroll
        for (int e = 0; e < 16; ++e){
            int idx = e*256 + tid;
            int r = idx >> 6, cc = idx & 63;
            T[cc][r] = (bf16)rd_any(in, (long)(k0 + r)*512 + n0 + cc, f);
        }
        __syncthreads();
        #pragma unroll
        for (int e = 0; e < 16; ++e){
            int idx = e*256 + tid;
            int rn = idx >> 6, ck = idx & 63;
            out[(long)(n0 + rn)*512 + k0 + ck] = T[rn][ck];
        }
    } else if (blk < 136){
        int sub = blk - 128;
        for (int i = tid; i < 1024; i += 256){
            int gi = sub*1024 + i;
            int n = gi >> 9, k = gi & 511;
            float v = (n < 8) ? rd_any(We, (long)k*8 + n, f)
                              : rd_any(Ws, (long)k*8 + (n-8), f);
            Wt_es[gi] = (bf16)v;
        }
    } else {
        int sub = blk - 136;
        int base = sub * 1024;
        for (int i = tid; i < 1024; i += 256){
            int gi = base + i;
            float x = rd_any(op, gi, f);
            float ls = (x < 0.f) ? (x - log1pf(expf(x))) : (0.f - log1pf(expf(-x)));
            o_buf[gi]    = expf(ls * (1.0f/16.0f));       // o = sigmoid^(1/16)
            oL_buf[gi]   = expf(ls * 2.0f);               // o^32
            lsL_buf[gi]  = ls * 2.0f;                     // log(o^32)
            oL16_buf[gi] = expf(ls * 32.0f);              // o^512
        }
        if (sub == 0){
            for (int i = tid; i < 512; i += 256){
                g_c[i] = rd_any(g, i, f);
                b_c[i] = rd_any(bta, i, f);
            }
        }
    }
}

// ---- GEMM: C(MxN) = A(MxK) * Bt(NxK)^T, bf16 MFMA, 2-phase dbuf pipeline ----
// Fused extras (gemm1 only):
//  * e/s projection: waves 0,2 of EVERY block accumulate A x Wt_es; global
//    e/s written only by ntile==0 blocks.
//  * chunk-local scan (ex-passA): the block's 128 rows are 4 aligned chunks;
//    after the k-loop the C-tile (bf16) + e are staged to LDS (aliasing the
//    dead As/Bs) and each block writes Ams for its (4 chunks x 128 dims).
__global__ __launch_bounds__(256) void gemm_bt(const void* __restrict__ Avoid,
                                               const bf16* __restrict__ Bt,
                                               void* __restrict__ Cvoid,
                                               int M, int N, int Kd,
                                               const int* __restrict__ aflag,
                                               const int* __restrict__ cflag,
                                               const bf16* __restrict__ Wes,
                                               float* __restrict__ e_out,
                                               float* __restrict__ s_out,
                                               float* __restrict__ Ams,
                                               const float* __restrict__ o_buf){
    __shared__ __align__(16) char smem[36*1024];
    bf16*  As = (bf16*)smem;              // [2][4096] (k-loop)
    bf16*  Bs = (bf16*)(smem + 16384);    // [2][4096] (k-loop)
    bf16*  iT = (bf16*)smem;              // [128][128] (scan phase, aliases As/Bs)
    float* eS = (float*)(smem + 32768);   // [128][8]
    const int tid  = threadIdx.x;
    const int lane = tid & 63;
    const int wave = tid >> 6;
    const int ntiles = N >> 7;
    // XCD-bijective swizzle: colocate the ntile-blocks of one mtile on one XCD
    // so the shared A panel is an L2 hit, not 4x cross-XCD refetch. 512%8==0.
    int bid = blockIdx.x;
    {
        const int q = gridDim.x >> 3;
        bid = (bid & 7) * q + (bid >> 3);
    }
    const int mtile = bid / ntiles;
    const int ntile = bid - mtile*ntiles;
    const int m0 = mtile << 7, n0 = ntile << 7;
    const int wr = (wave >> 1) << 6;
    const int wc = (wave & 1) << 6;
    const int lrow = lane & 15;
    const int quad = lane >> 4;
    const int fa = aflag ? *aflag : 0;
    const bool do_es = (Wes != nullptr) && ((wave & 1) == 0);

    f32x4 acc[4][4] = {};
    f32x4 acc_es[4] = {};

    const int sr = tid >> 2;              // staging row 0..63
    const int sk = (tid & 3) << 3;        // k offset 0/8/16/24
    const bf16*  Ag  = (const bf16*) Avoid + (long)(m0 + sr)*Kd + sk;
    const float* Agf = (const float*)Avoid + (long)(m0 + sr)*Kd + sk;
    const bf16*  Bg  = Bt + (long)(n0 + sr)*Kd + sk;

    // prologue: stage tile 0 into buffer 0
    if (fa){
        *(uint4*)&As[tid*8]        = cvt8(Agf);
        *(uint4*)&As[2048 + tid*8] = cvt8(Agf + (long)64*Kd);
    } else {
        cp16(Ag,                 As + (size_t)wave*512);
        cp16(Ag + (long)64*Kd,   As + 2048 + (size_t)wave*512);
    }
    cp16(Bg,               Bs + (size_t)wave*512);
    cp16(Bg + (long)64*Kd, Bs + 2048 + (size_t)wave*512);
    __syncthreads();                      // implicit vmcnt(0)+lgkmcnt(0) drain

    int cur = 0;
    for (int k0 = 0; k0 < Kd; k0 += 32){
        const int nxt  = cur ^ 1;
        const int k1   = k0 + 32;
        const bool more = (k1 < Kd);
        float4 la0, la1, lb0, lb1;
        if (more){
            if (fa){
                // issue raw fp32 loads now; convert+ds_write after the MFMAs
                la0 = *(const float4*)(Agf + k1);
                la1 = *(const float4*)(Agf + k1 + 4);
                lb0 = *(const float4*)(Agf + (long)64*Kd + k1);
                lb1 = *(const float4*)(Agf + (long)64*Kd + k1 + 4);
            } else {
                cp16(Ag + k1,               As + nxt*4096 + (size_t)wave*512);
                cp16(Ag + (long)64*Kd + k1, As + nxt*4096 + 2048 + (size_t)wave*512);
            }
            cp16(Bg + k1,               Bs + nxt*4096 + (size_t)wave*512);
            cp16(Bg + (long)64*Kd + k1, Bs + nxt*4096 + 2048 + (size_t)wave*512);
        }

        bf16x8 af[4], bfr[4];
        #pragma unroll
        for (int i = 0; i < 4; ++i)
            af[i]  = *(const bf16x8*)&As[cur*4096 + (wr + i*16 + lrow)*32 + quad*8];
        #pragma unroll
        for (int j = 0; j < 4; ++j)
            bfr[j] = *(const bf16x8*)&Bs[cur*4096 + (wc + j*16 + lrow)*32 + quad*8];
        #pragma unroll
        for (int i = 0; i < 4; ++i)
            #pragma unroll
            for (int j = 0; j < 4; ++j)
                acc[i][j] = __builtin_amdgcn_mfma_f32_16x16x32_bf16(af[i], bfr[j], acc[i][j], 0, 0, 0);
        if (do_es){
            bf16x8 be = *(const bf16x8*)(Wes + (long)lrow*512 + k0 + quad*8);
            #pragma unroll
            for (int i = 0; i < 4; ++i)
                acc_es[i] = __builtin_amdgcn_mfma_f32_16x16x32_bf16(af[i], be, acc_es[i], 0, 0, 0);
        }

        if (more && fa){
            uint4 A0, A1;
            A0.x = pack2(la0.x, la0.y); A0.y = pack2(la0.z, la0.w);
            A0.z = pack2(la1.x, la1.y); A0.w = pack2(la1.z, la1.w);
            A1.x = pack2(lb0.x, lb0.y); A1.y = pack2(lb0.z, lb0.w);
            A1.z = pack2(lb1.x, lb1.y); A1.w = pack2(lb1.z, lb1.w);
            *(uint4*)&As[nxt*4096 + tid*8]        = A0;
            *(uint4*)&As[nxt*4096 + 2048 + tid*8] = A1;
        }
        __syncthreads();                  // tile t reads done + tile t+1 staged
        cur = nxt;
    }

    const int fc = cflag ? *cflag : 0;
    // C/D layout: col = lane&15, row = quad*4 + reg
    if (fc){
        float* Cf = (float*)Cvoid;
        #pragma unroll
        for (int i = 0; i < 4; ++i){
            int gr = m0 + wr + i*16 + quad*4;
            #pragma unroll
            for (int j = 0; j < 4; ++j){
                int gc = n0 + wc + j*16 + lrow;
                #pragma unroll
                for (int r = 0; r < 4; ++r)
                    Cf[(long)(gr + r)*N + gc] = acc[i][j][r];
            }
        }
    } else {
        bf16* Cb = (bf16*)Cvoid;
        #pragma unroll
        for (int i = 0; i < 4; ++i){
            int gr = m0 + wr + i*16 + quad*4;
            #pragma unroll
            for (int j = 0; j < 4; ++j){
                int gc = n0 + wc + j*16 + lrow;
                #pragma unroll
                for (int r = 0; r < 4; ++r)
                    Cb[(long)(gr + r)*N + gc] = (bf16)acc[i][j][r];
            }
        }
    }
    if (do_es && ntile == 0){
        // D: col=lane&15 (0..7 -> e, 8..15 -> s), row = quad*4 + reg
        float* eo = (lrow < 8) ? e_out : s_out;
        int col = lrow & 7;
        #pragma unroll
        for (int i = 0; i < 4; ++i){
            int gr = m0 + wr + i*16 + quad*4;
            #pragma unroll
            for (int r = 0; r < 4; ++r)
                eo[(long)(gr + r)*8 + col] = acc_es[i][r];
        }
    }

    // ---- fused chunk-local scan (ex-passA) ----
    if (Ams){
        // stage i-tile (bf16, same rounding as global C) into LDS; As/Bs dead
        #pragma unroll
        for (int i = 0; i < 4; ++i){
            int lr = wr + i*16 + quad*4;
            #pragma unroll
            for (int j = 0; j < 4; ++j){
                int lc = wc + j*16 + lrow;
                #pragma unroll
                for (int r = 0; r < 4; ++r)
                    iT[(lr + r)*128 + lc] = (bf16)acc[i][j][r];
            }
        }
        if (do_es && lrow < 8){
            #pragma unroll
            for (int i = 0; i < 4; ++i){
                int lr = wr + i*16 + quad*4;
                #pragma unroll
                for (int r = 0; r < 4; ++r)
                    eS[(lr + r)*8 + lrow] = acc_es[i][r];
            }
        }
        __syncthreads();
        // thread -> (2 dims, 2 ks); 64 d-pairs x 4 k-pairs = 256 threads
        const int dp  = tid & 63;
        const int kq  = tid >> 6;
        const int dl  = dp*2;
        const int ki  = kq*2;
        const float o00 = o_buf[(ki  )*512 + n0 + dl];
        const float o01 = o_buf[(ki  )*512 + n0 + dl + 1];
        const float o10 = o_buf[(ki+1)*512 + n0 + dl];
        const float o11 = o_buf[(ki+1)*512 + n0 + dl + 1];
        #pragma unroll
        for (int c = 0; c < 4; ++c){
            float m00 = 0.f, m01 = 0.f, m10 = 0.f, m11 = 0.f;
            for (int t = 0; t < CHUNK; ++t){
                int row = c*32 + t;
                uint32_t iv = *(const uint32_t*)&iT[row*128 + dl];
                float i0 = bf2f((uint16_t)iv), i1 = bf2f((uint16_t)(iv >> 16));
                float e0 = eS[row*8 + ki], e1 = eS[row*8 + ki + 1];
                m00 = o00*m00 + e0*i0;  m01 = o01*m01 + e0*i1;
                m10 = o10*m10 + e1*i0;  m11 = o11*m11 + e1*i1;
            }
            float* Ac = Ams + (long)((m0 >> 5) + c)*4096 + n0 + dl;
            float2 v0; v0.x = m00; v0.y = m01;
            float2 v1; v1.x = m10; v1.y = m11;
            *(float2*)&Ac[(ki  )*512] = v0;
            *(float2*)&Ac[(ki+1)*512] = v1;
        }
    }
}

// ---- B1: in-place local prefix within each 16-chunk segment + totals ----
__global__ __launch_bounds__(256) void passB1(float* __restrict__ Ams,
                                              const float* __restrict__ oL_buf,
                                              float* __restrict__ Tbuf){
    int bs  = blockIdx.x >> 4;                       // b*8+seg, 0..31
    int b   = bs >> 3, seg = bs & 7;
    int idx = (blockIdx.x & 15)*256 + threadIdx.x;   // 0..4095
    float oL = oL_buf[idx];
    float m = 0.f;
    float* Mb = Ams + ((long)b*NCHUNKS_B + seg*SEGLEN)*4096 + idx;
    #pragma unroll 4
    for (int cc = 0; cc < SEGLEN; ++cc){
        float a = Mb[(long)cc*4096];
        Mb[(long)cc*4096] = m;
        m = oL*m + a;
    }
    Tbuf[(long)bs*4096 + idx] = m;
}

// ---- pass C: segment fixup (ex-passB2, from raw totals) + replay + LayerNorm ----
__global__ __launch_bounds__(256) void passC(bf16* __restrict__ iy,
                                             const float* __restrict__ e_buf,
                                             const float* __restrict__ s_buf,
                                             const float* __restrict__ o_buf,
                                             const float* __restrict__ Ploc,
                                             const float* __restrict__ Tbuf,
                                             const float* __restrict__ lsL_buf,
                                             const float* __restrict__ oL16_buf,
                                             const float* __restrict__ g_c,
                                             const float* __restrict__ b_c){
    int c  = blockIdx.x;
    int b  = c >> 7;
    int cI = c & 127;
    int seg = cI >> 4;
    float fj = (float)(cI & 15);
    int t0 = cI * CHUNK;
    int tid = threadIdx.x;
    __shared__ float eS[CHUNK*8], sS[CHUNK*8];
    __shared__ float muS[CHUNK], rS[CHUNK];
    __shared__ __align__(16) float yS[CHUNK][YSTRIDE];
    eS[tid] = e_buf[((long)(b*NSEQ + t0))*8 + tid];
    sS[tid] = s_buf[((long)(b*NSEQ + t0))*8 + tid];
    __syncthreads();
    int d0 = tid*2;
    float o0[8], o1[8], m0[8], m1[8];
    const float* P0 = Ploc + (long)c*4096;
    #pragma unroll
    for (int k = 0; k < 8; ++k){
        int i0 = k*512 + d0;
        // ex-passB2: segment-start state from raw segment totals (same FMA order)
        float ms0 = 0.f, ms1 = 0.f;
        float w0 = oL16_buf[i0], w1 = oL16_buf[i0+1];
        for (int u = 0; u < seg; ++u){
            const float* T = Tbuf + ((long)(b*NSEG + u))*4096;
            ms0 = w0*ms0 + T[i0];
            ms1 = w1*ms1 + T[i0+1];
        }
        o0[k] = o_buf[i0]; o1[k] = o_buf[i0 + 1];
        m0[k] = P0[i0]   + __expf(lsL_buf[i0]  *fj)*ms0;
        m1[k] = P0[i0+1] + __expf(lsL_buf[i0+1]*fj)*ms1;
    }
    bf16* ip = iy + (long)(b*NSEQ + t0)*512 + d0;
    for (int t = 0; t < CHUNK; ++t){
        uint32_t iv = *(const uint32_t*)(ip + (long)t*512);
        float i0 = bf2f((uint16_t)iv), i1 = bf2f((uint16_t)(iv >> 16));
        float y0 = 0.f, y1 = 0.f;
        #pragma unroll
        for (int k = 0; k < 8; ++k){
            float ek = eS[t*8 + k], sk = sS[t*8 + k];
            m0[k] = o0[k]*m0[k] + ek*i0;
            m1[k] = o1[k]*m1[k] + ek*i1;
            y0 += sk*m0[k];
            y1 += sk*m1[k];
        }
        float2 yv; yv.x = y0; yv.y = y1;
        *(float2*)&yS[t][d0] = yv;
    }
    __syncthreads();
    {
        int row = tid >> 3, sub = tid & 7;
        const float4* yr = (const float4*)&yS[row][sub*64];
        float s = 0.f, s2 = 0.f;
        #pragma unroll
        for (int j = 0; j < 16; ++j){
            float4 v = yr[j];
            s  += v.x + v.y + v.z + v.w;
            s2 += v.x*v.x + v.y*v.y + v.z*v.z + v.w*v.w;
        }
        s += __shfl_xor(s, 1); s2 += __shfl_xor(s2, 1);
        s += __shfl_xor(s, 2); s2 += __shfl_xor(s2, 2);
        s += __shfl_xor(s, 4); s2 += __shfl_xor(s2, 4);
        if (sub == 0){
            float mu  = s * (1.f/512.f);
            float var = s2 * (1.f/512.f) - mu*mu;
            muS[row] = mu;
            rS[row]  = rsqrtf(var + 1e-5f);
        }
    }
    __syncthreads();
    float g0 = g_c[d0], g1 = g_c[d0+1];
    float bb0 = b_c[d0], bb1 = b_c[d0+1];
    for (int t = 0; t < CHUNK; ++t){
        float mu = muS[t], r = rS[t];
        float2 yv = *(const float2*)&yS[t][d0];
        float a0 = (yv.x - mu)*r*g0 + bb0;
        float a1 = (yv.y - mu)*r*g1 + bb1;
        *(uint32_t*)(ip + (long)t*512) = pack2(a0, a1);
    }
}

extern "C" void kernel_launch(void* const* d_in, const int* in_sizes, int n_in,
                              void* d_out, int out_size, void* d_ws, size_t ws_size,
                              hipStream_t stream){
    const void* x    = d_in[0];
    const void* W_i  = d_in[1];
    const void* W_e  = d_in[2];
    const void* W_s  = d_in[3];
    const void* o_p  = d_in[4];
    const void* gmm  = d_in[5];
    const void* bta  = d_in[6];
    const void* W_o  = d_in[7];

    char* ws = (char*)d_ws;
    bf16*  Wt_i   = (bf16*) (ws + 0);          // 512 KB (dead after gemm1)
    float* Tbuf   = (float*)(ws + 0);          // aliased: B1 raw segment totals
    bf16*  Wt_o   = (bf16*) (ws + 524288);     // 512 KB
    bf16*  iy_buf = (bf16*) (ws + 1048576);    // 16 MB (i, then y in-place)
    float* e_buf  = (float*)(ws + 17825792);   // 512 KB
    float* s_buf  = (float*)(ws + 18350080);   // 512 KB
    float* o_buf  = (float*)(ws + 18874368);   // 16 KB
    float* oL_buf = (float*)(ws + 18890752);   // 16 KB
    float* lsL    = (float*)(ws + 18907136);   // 16 KB
    float* oL16   = (float*)(ws + 18923520);   // 16 KB
    float* Ams    = (float*)(ws + 18939904);   // 8 MB (A states, then local prefixes)
    bf16*  Wt_es  = (bf16*) (ws + 27328512);   // 16 KB
    float* g_c    = (float*)(ws + 27344896);   // 2 KB
    float* b_c    = (float*)(ws + 27346944);   // 2 KB
    int*   flag   = (int*)  (ws + 27348992);   // 256 B  (total ~26.1 MB)

    prep_all<<<140, 256, 0, stream>>>((const uint32_t*)x, W_i, W_o, W_e, W_s, o_p, gmm, bta,
                                      Wt_i, Wt_o, Wt_es, g_c, b_c, o_buf, oL_buf, lsL, oL16, flag);
    gemm_bt <<<512, 256, 0, stream>>>(x, Wt_i, iy_buf, NROWS, 512, 512, flag, nullptr,
                                      Wt_es, e_buf, s_buf, Ams, o_buf);
    passB1 <<<512,  256, 0, stream>>>(Ams, oL_buf, Tbuf);
    passC  <<<NCHUNKS, 256, 0, stream>>>(iy_buf, e_buf, s_buf, o_buf, Ams, Tbuf, lsL,
                                         oL16, g_c, b_c);
    gemm_bt <<<512, 256, 0, stream>>>(iy_buf, Wt_o, d_out, NROWS, 512, 512, nullptr, flag,
                                      nullptr, nullptr, nullptr, nullptr, nullptr);
}